// Round 2
// baseline (6050.438 us; speedup 1.0000x reference)
//
#include <hip/hip_runtime.h>
#include <math.h>

#define BATCH 4
#define HH 512
#define WW 1024
#define NPIX (HH*WW)          // 524288 = 2^19
#define CCAP 196608           // compaction capacity per image (expected ~161.7k valid)
#define NW64 (CCAP/64)        // 3072 bitmask words

// ---------------- XLA:CPU f32 math replicas ----------------
// tanh: XLA/Eigen rational approx, FMA-contracted Horner (fast-math flags set in
// XLA's vector emitter -> AVX2 FMA on the CPU that produced the expected output).
__device__ __forceinline__ float xla_tanhf(float x) {
  if (fabsf(x) < 0.0004f) return x;               // kCanUseApprox branch
  float xc = fminf(fmaxf(x, -7.90531110763549805f), 7.90531110763549805f);
  float x2 = __fmul_rn(xc, xc);
  float p = -2.76076847742355e-16f;
  p = fmaf(x2, p, 2.00018790482477e-13f);
  p = fmaf(x2, p, -8.60467152213735e-11f);
  p = fmaf(x2, p, 5.12229709037114e-08f);
  p = fmaf(x2, p, 1.48572235717979e-05f);
  p = fmaf(x2, p, 6.37261928875436e-04f);
  p = fmaf(x2, p, 4.89352455891786e-03f);
  p = __fmul_rn(xc, p);
  float q = fmaf(x2, 1.19825839466702e-06f, 1.18534705686654e-04f);
  q = fmaf(x2, q, 2.26843463243900e-03f);
  q = fmaf(x2, q, 4.89352518554385e-03f);
  return __fdiv_rn(p, q);
}

// exp: Cephes/Eigen f32 exp (range reduce by ln2 in two parts, degree-5 poly), fused.
__device__ __forceinline__ float xla_expf(float x) {
  float xc = fminf(fmaxf(x, -87.3365478515625f), 88.72283935546875f);
  float m = floorf(fmaf(xc, 1.44269504088896341f, 0.5f));
  float r = fmaf(m, -0.693359375f, xc);
  r = fmaf(m, 2.12194440e-4f, r);
  float r2 = __fmul_rn(r, r);
  float p = 1.9875691500e-4f;
  p = fmaf(p, r, 1.3981999507e-3f);
  p = fmaf(p, r, 8.3334519073e-3f);
  p = fmaf(p, r, 4.1665795894e-2f);
  p = fmaf(p, r, 1.6666665459e-1f);
  p = fmaf(p, r, 5.0000001201e-1f);
  float y = fmaf(r2, p, r);
  y = __fadd_rn(y, 1.0f);
  return ldexpf(y, (int)m);
}

// jax.nn.sigmoid -> lax.logistic -> XLA LogisticExpander: 0.5 + 0.5*tanh(0.5*x)
__device__ __forceinline__ float xla_sigmoidf(float x) {
  return fmaf(0.5f, xla_tanhf(__fmul_rn(0.5f, x)), 0.5f);
}

// ---------------- block helpers ----------------

__device__ __forceinline__ void block_argmax(float &sm, int &px, int &ci,
                                             float* r_f, int* r_p, int* r_c) {
  int tid = threadIdx.x; int lane = tid & 63; int wid = tid >> 6;
  for (int off = 32; off > 0; off >>= 1) {
    float o_sm = __shfl_down(sm, off);
    int   o_px = __shfl_down(px, off);
    int   o_ci = __shfl_down(ci, off);
    if (o_sm > sm || (o_sm == sm && o_px < px)) { sm = o_sm; px = o_px; ci = o_ci; }
  }
  if (lane == 0) { r_f[wid] = sm; r_p[wid] = px; r_c[wid] = ci; }
  __syncthreads();
  if (wid == 0) {
    if (lane < 16) { sm = r_f[lane]; px = r_p[lane]; ci = r_c[lane]; }
    else { sm = -1e30f; px = 0x7fffffff; ci = -1; }
    for (int off = 8; off > 0; off >>= 1) {
      float o_sm = __shfl_down(sm, off);
      int   o_px = __shfl_down(px, off);
      int   o_ci = __shfl_down(ci, off);
      if (o_sm > sm || (o_sm == sm && o_px < px)) { sm = o_sm; px = o_px; ci = o_ci; }
    }
    if (lane == 0) { r_f[0] = sm; r_p[0] = px; r_c[0] = ci; }
  }
  __syncthreads();
  sm = r_f[0]; px = r_p[0]; ci = r_c[0];
  __syncthreads();
}

__device__ __forceinline__ void block_reduce2(int &a, int &b, int* r_i) {
  int tid = threadIdx.x; int lane = tid & 63; int wid = tid >> 6;
  for (int off = 32; off > 0; off >>= 1) {
    a += __shfl_down(a, off);
    b += __shfl_down(b, off);
  }
  if (lane == 0) { r_i[wid] = a; r_i[16 + wid] = b; }
  __syncthreads();
  if (wid == 0) {
    a = (lane < 16) ? r_i[lane] : 0;
    b = (lane < 16) ? r_i[16 + lane] : 0;
    for (int off = 8; off > 0; off >>= 1) {
      a += __shfl_down(a, off);
      b += __shfl_down(b, off);
    }
    if (lane == 0) { r_i[0] = a; r_i[16] = b; }
  }
  __syncthreads();
  a = r_i[0]; b = r_i[16];
  __syncthreads();
}

// ---------------- kernels ----------------

__global__ __launch_bounds__(1024) void fill_kernel(int* out, int val, int n) {
  int i = blockIdx.x * 1024 + threadIdx.x;
  if (i < n) out[i] = val;
}

__global__ __launch_bounds__(256) void prep_kernel(const float* __restrict__ in,
                                                   int* __restrict__ out,
                                                   float2* __restrict__ emb,
                                                   int2* __restrict__ pk,
                                                   int* __restrict__ cnt) {
  int gid = blockIdx.x * 256 + threadIdx.x;      // exactly BATCH*NPIX threads
  int b = gid >> 19;
  int p = gid & (NPIX - 1);
  const float* base = in + (size_t)b * 5 * NPIX;
  float seed = base[(size_t)4 * NPIX + p];
  out[gid] = 0;                                   // int32 output, zero-init
  bool valid = seed > 0.5f;
  unsigned long long mask = __ballot(valid);
  if (valid) {
    int lane = threadIdx.x & 63;
    int leader = __builtin_ctzll(mask);
    int basecnt = 0;
    if (lane == leader) basecnt = atomicAdd(&cnt[b], (int)__popcll(mask));
    basecnt = __shfl(basecnt, leader);
    int slot = basecnt + (int)__popcll(mask & ((1ULL << lane) - 1ULL));
    if (slot < CCAP) {
      float ox = base[p];
      float oy = base[(size_t)NPIX + p];
      int col = p & (WW - 1);
      int row = p >> 10;
      // jax f32 linspace: out[i] = f32(i) * (f32(span)/f32(n-1)); endpoints land
      // exactly on 2.0 / 1.0 (verified by rounding analysis), no fixup needed.
      float gx = __fmul_rn((float)col, 2.0f / 1023.0f);
      float gy = __fmul_rn((float)row, 1.0f / 511.0f);
      float ex = __fadd_rn(xla_tanhf(ox), gx);
      float ey = __fadd_rn(xla_tanhf(oy), gy);
      float smv = xla_sigmoidf(seed);
      emb[(size_t)b * CCAP + slot] = make_float2(ex, ey);
      pk[(size_t)b * CCAP + slot]  = make_int2(__float_as_int(smv), p);
    }
  }
}

// One workgroup per image: the sequential greedy clustering loop.
__global__ __launch_bounds__(1024) void cluster_kernel(const float* __restrict__ in,
                                                       int* __restrict__ out,
                                                       const float2* __restrict__ emb_all,
                                                       const int2* __restrict__ pk_all,
                                                       const int* __restrict__ cnt) {
  __shared__ unsigned long long s_uncl[NW64];   // 24 KB
  __shared__ unsigned long long s_prop[NW64];   // 24 KB
  __shared__ float r_f[16];
  __shared__ int   r_p[16];
  __shared__ int   r_c[16];
  __shared__ int   r_i[32];
  __shared__ float bc_f[8];

  int b = blockIdx.x;
  int tid = threadIdx.x;
  int lane = tid & 63;
  int V = cnt[b];
  const float2* emb = emb_all + (size_t)b * CCAP;
  const int2*   pk  = pk_all  + (size_t)b * CCAP;
  int* outb = out + (size_t)b * NPIX;
  const float* sig0 = in + (size_t)b * 5 * NPIX + (size_t)2 * NPIX;
  const float* sig1 = in + (size_t)b * 5 * NPIX + (size_t)3 * NPIX;

  if (V > CCAP) {  // capacity overflow marker (diagnosable via absmax)
    for (int i = tid; i < NPIX; i += 1024) outb[i] = 1000000;
    return;
  }

  int Vpad = (V + 1023) & ~1023;

  for (int w = tid; w < NW64; w += 1024) {
    int basebit = w << 6;
    unsigned long long m;
    if (basebit + 64 <= V)      m = ~0ULL;
    else if (basebit >= V)      m = 0ULL;
    else                        m = (1ULL << (V - basebit)) - 1ULL;
    s_uncl[w] = m;
  }
  __syncthreads();

  int ucount = V;
  int count = 1;

  // initial argmax (all valid pixels unclustered; tie -> lowest original index)
  float bsm = -1.0f; int bpx = 0x7fffffff; int bci = -1;
  for (int i = tid; i < V; i += 1024) {
    int2 v = pk[i];
    float smv = __int_as_float(v.x);
    if (smv > bsm || (smv == bsm && v.y < bpx)) { bsm = smv; bpx = v.y; bci = i; }
  }
  block_argmax(bsm, bpx, bci, r_f, r_p, r_c);

  int guard = 0;
  while (ucount > 64 && guard++ <= CCAP) {
    if (bsm < 0.5f) break;   // ref's new_done (provably never fires)

    if (tid == 0) {
      float2 c = emb[bci];
      float sx = sig0[bpx];
      float sy = sig1[bpx];
      float den0 = __fmul_rn(2.0f, __fmul_rn(sx, sx));   // ref: 2.0 * s**2
      float den1 = __fmul_rn(2.0f, __fmul_rn(sy, sy));
      bc_f[0] = c.x; bc_f[1] = c.y;
      bc_f[2] = den0; bc_f[3] = den1;
      bc_f[4] = 1.0f / den0;           // screening reciprocals (fast path only)
      bc_f[5] = 1.0f / den1;
      s_uncl[bci >> 6] &= ~(1ULL << (bci & 63));  // uncl2 = uncl \ {idx}
    }
    __syncthreads();
    float cx = bc_f[0], cy = bc_f[1];
    float den0 = bc_f[2], den1 = bc_f[3];
    float inv0 = bc_f[4], inv1 = bc_f[5];

    // ---- pass 1: proposal + counts ----
    int pc = 0, uc = 0;
    for (int i = tid; i < Vpad; i += 1024) {
      bool p = false;
      if (i < V) {
        float2 e = emb[i];
        float d0 = __fsub_rn(e.x, cx), d1 = __fsub_rn(e.y, cy);
        float dd0 = __fmul_rn(d0, d0), dd1 = __fmul_rn(d1, d1);
        float zf = fmaf(dd0, inv0, __fmul_rn(dd1, inv1));    // fast screen
        if (zf < 0.6921472f) p = true;                       // z < ln2 - 1e-3: certain
        else if (zf <= 0.6941472f) {                         // boundary window +-1e-3
          // exact ref replication: f32 div, f32 add, Cephes exp, > 0.5
          float t0 = __fdiv_rn(dd0, den0);
          float t1 = __fdiv_rn(dd1, den1);
          float z = __fadd_rn(t0, t1);
          p = (xla_expf(-z) > 0.5f);
        }
      }
      unsigned long long pmask = __ballot(p);
      int w = i >> 6;
      if (lane == 0) s_prop[w] = pmask;
      unsigned long long um = s_uncl[w];
      pc += (int)p;
      uc += (int)(p && ((um >> lane) & 1ULL));
    }
    block_reduce2(pc, uc, r_i);

    bool accept = (pc > 64) && (2 * uc > pc);
    int label = count & 255;                 // ref casts to uint8 at the end
    if (accept) count++;
    ucount -= (1 + uc);

    // ---- pass 2: apply removal, write labels, fused next argmax ----
    bsm = -1.0f; bpx = 0x7fffffff; bci = -1;
    for (int i = tid; i < Vpad; i += 1024) {
      int w = i >> 6;
      unsigned long long um = s_uncl[w];
      unsigned long long pm = s_prop[w];
      unsigned long long keep = um & ~pm;
      if (keep != um && lane == 0) s_uncl[w] = keep;
      bool nb = (keep >> lane) & 1ULL;
      bool pb = (pm >> lane) & 1ULL;
      bool need = nb || (accept && pb);
      if (need) {
        int2 v = pk[i];
        if (accept && pb) outb[v.y] = label;
        if (nb) {
          float smv = __int_as_float(v.x);
          if (smv > bsm || (smv == bsm && v.y < bpx)) { bsm = smv; bpx = v.y; bci = i; }
        }
      }
    }
    block_argmax(bsm, bpx, bci, r_f, r_p, r_c);
  }
}

// ---------------- launch ----------------

extern "C" void kernel_launch(void* const* d_in, const int* in_sizes, int n_in,
                              void* d_out, int out_size, void* d_ws, size_t ws_size,
                              hipStream_t stream) {
  const float* in = (const float*)d_in[0];
  int* out = (int*)d_out;

  size_t emb_bytes = (size_t)BATCH * CCAP * sizeof(float2);
  size_t pk_bytes  = (size_t)BATCH * CCAP * sizeof(int2);
  size_t need = 64 + emb_bytes + pk_bytes;   // ~12.6 MB

  if (ws_size < need) {
    fill_kernel<<<(out_size + 1023) / 1024, 1024, 0, stream>>>(out, 2000000, out_size);
    return;
  }

  int*    cnt = (int*)d_ws;
  float2* emb = (float2*)((char*)d_ws + 64);
  int2*   pk  = (int2*)((char*)d_ws + 64 + emb_bytes);

  hipMemsetAsync(d_ws, 0, 64, stream);
  prep_kernel<<<(BATCH * NPIX) / 256, 256, 0, stream>>>(in, out, emb, pk, cnt);
  cluster_kernel<<<BATCH, 1024, 0, stream>>>(in, out, emb, pk, cnt);
}

// Round 3
// 1729.610 us; speedup vs baseline: 3.4982x; 3.4982x over previous
//
#include <hip/hip_runtime.h>
#include <math.h>

#define BATCH 4
#define HH 512
#define WW 1024
#define NPIX (HH*WW)          // 524288 = 2^19
#define CCAP 196608           // compaction capacity per image (expected ~161.7k valid)
#define GX 64
#define GY 48
#define NCELL (GX*GY)         // 3072 cells, 0.0625 x 0.0625 over [-1,3]x[-1,2]
#define DLCAP 2048            // dirty-segment list capacity

// ---------------- XLA:CPU f32 math replicas (unchanged from passing round 2) ----
__device__ __forceinline__ float xla_tanhf(float x) {
  if (fabsf(x) < 0.0004f) return x;
  float xc = fminf(fmaxf(x, -7.90531110763549805f), 7.90531110763549805f);
  float x2 = __fmul_rn(xc, xc);
  float p = -2.76076847742355e-16f;
  p = fmaf(x2, p, 2.00018790482477e-13f);
  p = fmaf(x2, p, -8.60467152213735e-11f);
  p = fmaf(x2, p, 5.12229709037114e-08f);
  p = fmaf(x2, p, 1.48572235717979e-05f);
  p = fmaf(x2, p, 6.37261928875436e-04f);
  p = fmaf(x2, p, 4.89352455891786e-03f);
  p = __fmul_rn(xc, p);
  float q = fmaf(x2, 1.19825839466702e-06f, 1.18534705686654e-04f);
  q = fmaf(x2, q, 2.26843463243900e-03f);
  q = fmaf(x2, q, 4.89352518554385e-03f);
  return __fdiv_rn(p, q);
}

__device__ __forceinline__ float xla_expf(float x) {
  float xc = fminf(fmaxf(x, -87.3365478515625f), 88.72283935546875f);
  float m = floorf(fmaf(xc, 1.44269504088896341f, 0.5f));
  float r = fmaf(m, -0.693359375f, xc);
  r = fmaf(m, 2.12194440e-4f, r);
  float r2 = __fmul_rn(r, r);
  float p = 1.9875691500e-4f;
  p = fmaf(p, r, 1.3981999507e-3f);
  p = fmaf(p, r, 8.3334519073e-3f);
  p = fmaf(p, r, 4.1665795894e-2f);
  p = fmaf(p, r, 1.6666665459e-1f);
  p = fmaf(p, r, 5.0000001201e-1f);
  float y = fmaf(r2, p, r);
  y = __fadd_rn(y, 1.0f);
  return ldexpf(y, (int)m);
}

__device__ __forceinline__ float xla_sigmoidf(float x) {
  return fmaf(0.5f, xla_tanhf(__fmul_rn(0.5f, x)), 0.5f);
}

// Proposal test — byte-identical decision logic to the round-2 passing kernel.
__device__ __forceinline__ bool prop_test(float2 e, float cx, float cy,
                                          float den0, float den1,
                                          float inv0, float inv1) {
  float d0 = __fsub_rn(e.x, cx), d1 = __fsub_rn(e.y, cy);
  float dd0 = __fmul_rn(d0, d0), dd1 = __fmul_rn(d1, d1);
  float zf = fmaf(dd0, inv0, __fmul_rn(dd1, inv1));
  if (zf < 0.6921472f) return true;
  if (zf <= 0.6941472f) {
    float t0 = __fdiv_rn(dd0, den0);
    float t1 = __fdiv_rn(dd1, den1);
    float z = __fadd_rn(t0, t1);
    return xla_expf(-z) > 0.5f;
  }
  return false;
}

__device__ __forceinline__ int cell_of_x(float ex) {
  int c = (int)((ex + 1.0f) * 16.0f);
  return min(max(c, 0), GX - 1);
}
__device__ __forceinline__ int cell_of_y(float ey) {
  int c = (int)((ey + 1.0f) * 16.0f);
  return min(max(c, 0), GY - 1);
}

// ---------------- block helpers ----------------

__device__ __forceinline__ void block_reduce2(int &a, int &b, int* r_i) {
  int tid = threadIdx.x; int lane = tid & 63; int wid = tid >> 6;
  for (int off = 32; off > 0; off >>= 1) {
    a += __shfl_down(a, off);
    b += __shfl_down(b, off);
  }
  if (lane == 0) { r_i[wid] = a; r_i[16 + wid] = b; }
  __syncthreads();
  if (wid == 0) {
    a = (lane < 16) ? r_i[lane] : 0;
    b = (lane < 16) ? r_i[16 + lane] : 0;
    for (int off = 8; off > 0; off >>= 1) {
      a += __shfl_down(a, off);
      b += __shfl_down(b, off);
    }
    if (lane == 0) { r_i[0] = a; r_i[16] = b; }
  }
  __syncthreads();
  a = r_i[0]; b = r_i[16];
  __syncthreads();
}

// argmax over packed keys: key = (sm_bits << 32) | ~px  (first-max tie-break = min px)
__device__ __forceinline__ void block_argmax_key(unsigned long long &key, int &ci,
                                                 unsigned long long* r_k, int* r_c) {
  int tid = threadIdx.x; int lane = tid & 63; int wid = tid >> 6;
  for (int off = 32; off > 0; off >>= 1) {
    unsigned long long ok = __shfl_down(key, off);
    int oci = __shfl_down(ci, off);
    if (ok > key) { key = ok; ci = oci; }
  }
  if (lane == 0) { r_k[wid] = key; r_c[wid] = ci; }
  __syncthreads();
  if (wid == 0) {
    if (lane < 16) { key = r_k[lane]; ci = r_c[lane]; }
    else { key = 0ULL; ci = -1; }
    for (int off = 8; off > 0; off >>= 1) {
      unsigned long long ok = __shfl_down(key, off);
      int oci = __shfl_down(ci, off);
      if (ok > key) { key = ok; ci = oci; }
    }
    if (lane == 0) { r_k[0] = key; r_c[0] = ci; }
  }
  __syncthreads();
  key = r_k[0]; ci = r_c[0];
  __syncthreads();
}

// recompute cached argmax of one 64-pixel segment (one wave)
__device__ __forceinline__ void seg_scan(int s, int V, const int2* __restrict__ pk,
                                         const unsigned int* s_uncl,
                                         unsigned long long* s_segkey, int* s_segci) {
  int lane = threadIdx.x & 63;
  int i = (s << 6) + lane;
  unsigned long long key = 0ULL; int ci = -1;
  if (i < V) {
    unsigned int wv = s_uncl[i >> 5];
    if ((wv >> (i & 31)) & 1u) {
      int2 v = pk[i];
      key = ((unsigned long long)(unsigned int)v.x << 32) | (unsigned int)(~v.y);
      ci = i;
    }
  }
  for (int off = 32; off > 0; off >>= 1) {
    unsigned long long ok = __shfl_down(key, off);
    int oci = __shfl_down(ci, off);
    if (ok > key) { key = ok; ci = oci; }
  }
  if (lane == 0) { s_segkey[s] = key; s_segci[s] = ci; }
}

// ---------------- kernels ----------------

__global__ __launch_bounds__(1024) void fill_kernel(int* out, int val, int n) {
  int i = blockIdx.x * 1024 + threadIdx.x;
  if (i < n) out[i] = val;
}

// pass A: zero output, histogram valid pixels into embedding-space cells
__global__ __launch_bounds__(256) void hist_kernel(const float* __restrict__ in,
                                                   int* __restrict__ out,
                                                   int* __restrict__ hist) {
  int gid = blockIdx.x * 256 + threadIdx.x;
  int b = gid >> 19;
  int p = gid & (NPIX - 1);
  const float* base = in + (size_t)b * 5 * NPIX;
  float seed = base[(size_t)4 * NPIX + p];
  out[gid] = 0;
  if (seed > 0.5f) {
    float ox = base[p];
    float oy = base[(size_t)NPIX + p];
    int col = p & (WW - 1);
    int row = p >> 10;
    float gx = __fmul_rn((float)col, 2.0f / 1023.0f);
    float gy = __fmul_rn((float)row, 1.0f / 511.0f);
    float ex = __fadd_rn(xla_tanhf(ox), gx);
    float ey = __fadd_rn(xla_tanhf(oy), gy);
    atomicAdd(&hist[b * NCELL + cell_of_y(ey) * GX + cell_of_x(ex)], 1);
  }
}

// pass B: exclusive scan of the 3072 cell counts per image (one block per image)
__global__ __launch_bounds__(1024) void scan_kernel(const int* __restrict__ hist,
                                                    int* __restrict__ off,
                                                    int* __restrict__ cursor) {
  __shared__ int s_c[NCELL];
  __shared__ int s_ps[1024];
  int b = blockIdx.x, t = threadIdx.x;
  const int* h = hist + b * NCELL;
  for (int i = t; i < NCELL; i += 1024) s_c[i] = h[i];
  __syncthreads();
  int a = s_c[3 * t], b2 = s_c[3 * t + 1], c2 = s_c[3 * t + 2];
  int th = a + b2 + c2;
  s_ps[t] = th;
  __syncthreads();
  for (int d = 1; d < 1024; d <<= 1) {
    int v = (t >= d) ? s_ps[t - d] : 0;
    __syncthreads();
    s_ps[t] += v;
    __syncthreads();
  }
  int excl = s_ps[t] - th;
  int* ob = off + b * (NCELL + 1);
  int* cb = cursor + b * NCELL;
  ob[3 * t] = excl;            cb[3 * t] = excl;
  ob[3 * t + 1] = excl + a;    cb[3 * t + 1] = excl + a;
  ob[3 * t + 2] = excl + a + b2; cb[3 * t + 2] = excl + a + b2;
  if (t == 1023) ob[NCELL] = s_ps[1023];
}

// pass C: scatter valid pixels into cell-sorted order (recomputes emb; deterministic)
__global__ __launch_bounds__(256) void scatter_kernel(const float* __restrict__ in,
                                                      int* __restrict__ cursor,
                                                      float2* __restrict__ emb,
                                                      int2* __restrict__ pk) {
  int gid = blockIdx.x * 256 + threadIdx.x;
  int b = gid >> 19;
  int p = gid & (NPIX - 1);
  const float* base = in + (size_t)b * 5 * NPIX;
  float seed = base[(size_t)4 * NPIX + p];
  if (seed > 0.5f) {
    float ox = base[p];
    float oy = base[(size_t)NPIX + p];
    int col = p & (WW - 1);
    int row = p >> 10;
    float gx = __fmul_rn((float)col, 2.0f / 1023.0f);
    float gy = __fmul_rn((float)row, 1.0f / 511.0f);
    float ex = __fadd_rn(xla_tanhf(ox), gx);
    float ey = __fadd_rn(xla_tanhf(oy), gy);
    float smv = xla_sigmoidf(seed);
    int cell = cell_of_y(ey) * GX + cell_of_x(ex);
    int slot = atomicAdd(&cursor[b * NCELL + cell], 1);
    if (slot < CCAP) {
      emb[(size_t)b * CCAP + slot] = make_float2(ex, ey);
      pk[(size_t)b * CCAP + slot]  = make_int2(__float_as_int(smv), p);
    }
  }
}

// One workgroup per image: greedy loop with bbox-limited passes + cached segment argmax.
__global__ __launch_bounds__(1024) void cluster_kernel(const float* __restrict__ in,
                                                       int* __restrict__ out,
                                                       const float2* __restrict__ emb_all,
                                                       const int2* __restrict__ pk_all,
                                                       const int* __restrict__ off_g) {
  __shared__ unsigned int s_uncl[CCAP / 32];            // 24 KB
  __shared__ int s_off[NCELL + 1];                      // 12 KB
  __shared__ unsigned long long s_segkey[CCAP / 64];    // 24 KB
  __shared__ int s_segci[CCAP / 64];                    // 12 KB
  __shared__ int s_dirty[CCAP / 64];                    // 12 KB
  __shared__ int s_dlist[DLCAP];                        // 8 KB
  __shared__ unsigned long long r_k[16];
  __shared__ int r_c[16];
  __shared__ int r_i[32];
  __shared__ float bc_f[8];
  __shared__ int bc_i[8];
  __shared__ int s_nd[2];

  int b = blockIdx.x;
  int tid = threadIdx.x;
  int wid = tid >> 6;
  const int* offb = off_g + b * (NCELL + 1);
  int V = offb[NCELL];
  const float2* emb = emb_all + (size_t)b * CCAP;
  const int2*   pk  = pk_all  + (size_t)b * CCAP;
  int* outb = out + (size_t)b * NPIX;
  const float* sig0 = in + (size_t)b * 5 * NPIX + (size_t)2 * NPIX;
  const float* sig1 = in + (size_t)b * 5 * NPIX + (size_t)3 * NPIX;

  if (V > CCAP) {   // capacity overflow marker
    for (int i = tid; i < NPIX; i += 1024) outb[i] = 1000000;
    return;
  }
  int NSEG = (V + 63) >> 6;

  for (int i = tid; i <= NCELL; i += 1024) s_off[i] = offb[i];
  for (int w = tid; w < CCAP / 32; w += 1024) {
    int basebit = w << 5;
    unsigned m;
    if (basebit + 32 <= V)      m = 0xffffffffu;
    else if (basebit >= V)      m = 0u;
    else                        m = (1u << (V - basebit)) - 1u;
    s_uncl[w] = m;
  }
  for (int s = tid; s < CCAP / 64; s += 1024) s_dirty[s] = 0;
  __syncthreads();

  // build all segment argmax caches (one-time full scan)
  for (int d = wid; d < NSEG; d += 16) seg_scan(d, V, pk, s_uncl, s_segkey, s_segci);
  __syncthreads();

  unsigned long long key = 0ULL; int ci = -1;
  for (int s = tid; s < NSEG; s += 1024) {
    unsigned long long k = s_segkey[s];
    if (k > key) { key = k; ci = s_segci[s]; }
  }
  block_argmax_key(key, ci, r_k, r_c);

  int ucount = V, count = 1, guard = 0;
  while (ucount > 64 && guard++ <= CCAP) {
    float sm = __uint_as_float((unsigned)(key >> 32));
    if (ci < 0 || sm < 0.5f) break;     // ref's new_done (provably never fires)
    int px = (int)(~(unsigned)key);

    if (tid == 0) {
      float2 c = emb[ci];
      float sx = sig0[px];
      float sy = sig1[px];
      float den0 = __fmul_rn(2.0f, __fmul_rn(sx, sx));
      float den1 = __fmul_rn(2.0f, __fmul_rn(sy, sy));
      bc_f[0] = c.x; bc_f[1] = c.y; bc_f[2] = den0; bc_f[3] = den1;
      bc_f[4] = 1.0f / den0; bc_f[5] = 1.0f / den1;
      // conservative ellipse bbox (margin covers screen window + recip slop)
      float rx = sqrtf(__fmul_rn(den0, 0.6971472f));
      float ry = sqrtf(__fmul_rn(den1, 0.6971472f));
      bc_i[0] = cell_of_y(c.y - ry);  // r0
      bc_i[1] = cell_of_y(c.y + ry);  // r1
      bc_i[2] = cell_of_x(c.x - rx);  // c0
      bc_i[3] = cell_of_x(c.x + rx);  // c1
      s_uncl[ci >> 5] &= ~(1u << (ci & 31));   // uncl2 = uncl \ {idx}
      s_dirty[ci >> 6] = 1;
      s_nd[0] = 0; s_nd[1] = 0;
    }
    __syncthreads();
    float cx = bc_f[0], cy = bc_f[1];
    float den0 = bc_f[2], den1 = bc_f[3], inv0 = bc_f[4], inv1 = bc_f[5];
    int r0 = bc_i[0], r1 = bc_i[1], c0 = bc_i[2], c1 = bc_i[3];

    // ---- pass 1: pc/uc over bbox pixel ranges ----
    int pc = 0, uc = 0;
    for (int r = r0; r <= r1; ++r) {
      int rs = s_off[r * GX + c0], re = s_off[r * GX + c1 + 1];
      for (int i = rs + tid; i < re; i += 1024) {
        if (prop_test(emb[i], cx, cy, den0, den1, inv0, inv1)) {
          pc++;
          uc += (int)((s_uncl[i >> 5] >> (i & 31)) & 1u);
        }
      }
    }
    block_reduce2(pc, uc, r_i);

    bool accept = (pc > 64) && (2 * uc > pc);
    int label = count & 255;
    if (accept) count++;
    ucount -= (1 + uc);

    // ---- pass 2: label writes + removals + dirty marking ----
    for (int r = r0; r <= r1; ++r) {
      int rs = s_off[r * GX + c0], re = s_off[r * GX + c1 + 1];
      for (int i = rs + tid; i < re; i += 1024) {
        if (prop_test(emb[i], cx, cy, den0, den1, inv0, inv1)) {
          int2 v = pk[i];
          if (accept) outb[v.y] = label;
          unsigned wv = s_uncl[i >> 5];
          if ((wv >> (i & 31)) & 1u) {
            atomicAnd(&s_uncl[i >> 5], ~(1u << (i & 31)));
            s_dirty[i >> 6] = 1;
          }
        }
      }
    }
    __syncthreads();

    // ---- compact dirty segments (claim via atomicExch) ----
    for (int r = r0; r <= r1; ++r) {
      int rs = s_off[r * GX + c0], re = s_off[r * GX + c1 + 1];
      if (re <= rs) continue;
      int slo = rs >> 6, shi = (re - 1) >> 6;
      for (int s = slo + tid; s <= shi; s += 1024) {
        if (s_dirty[s]) {
          if (atomicExch(&s_dirty[s], 0) != 0) {
            int pos = atomicAdd(&s_nd[0], 1);
            if (pos < DLCAP) s_dlist[pos] = s; else s_nd[1] = 1;
          }
        }
      }
    }
    __syncthreads();

    // ---- recompute dirty segment caches ----
    if (s_nd[1]) {                       // overflow fallback (should never fire)
      for (int d = wid; d < NSEG; d += 16) seg_scan(d, V, pk, s_uncl, s_segkey, s_segci);
      for (int s = tid; s < CCAP / 64; s += 1024) s_dirty[s] = 0;
    } else {
      int nd = s_nd[0];
      for (int d = wid; d < nd; d += 16) seg_scan(s_dlist[d], V, pk, s_uncl, s_segkey, s_segci);
    }
    __syncthreads();

    // ---- next argmax from segment caches ----
    key = 0ULL; ci = -1;
    for (int s = tid; s < NSEG; s += 1024) {
      unsigned long long k = s_segkey[s];
      if (k > key) { key = k; ci = s_segci[s]; }
    }
    block_argmax_key(key, ci, r_k, r_c);
  }
}

// ---------------- launch ----------------

extern "C" void kernel_launch(void* const* d_in, const int* in_sizes, int n_in,
                              void* d_out, int out_size, void* d_ws, size_t ws_size,
                              hipStream_t stream) {
  const float* in = (const float*)d_in[0];
  int* out = (int*)d_out;

  size_t hist_bytes = (size_t)BATCH * NCELL * sizeof(int);          // 48 KB
  size_t off_bytes  = (size_t)BATCH * (NCELL + 1) * sizeof(int);    // 48 KB
  size_t cur_bytes  = (size_t)BATCH * NCELL * sizeof(int);          // 48 KB
  size_t emb_bytes  = (size_t)BATCH * CCAP * sizeof(float2);        // 6.3 MB
  size_t pk_bytes   = (size_t)BATCH * CCAP * sizeof(int2);          // 6.3 MB

  size_t o_hist = 256;
  size_t o_off  = (o_hist + hist_bytes + 255) & ~(size_t)255;
  size_t o_cur  = (o_off + off_bytes + 255) & ~(size_t)255;
  size_t o_emb  = (o_cur + cur_bytes + 255) & ~(size_t)255;
  size_t o_pk   = (o_emb + emb_bytes + 255) & ~(size_t)255;
  size_t need   = o_pk + pk_bytes;

  if (ws_size < need) {
    fill_kernel<<<(out_size + 1023) / 1024, 1024, 0, stream>>>(out, 2000000, out_size);
    return;
  }

  int*    hist = (int*)((char*)d_ws + o_hist);
  int*    off  = (int*)((char*)d_ws + o_off);
  int*    cur  = (int*)((char*)d_ws + o_cur);
  float2* emb  = (float2*)((char*)d_ws + o_emb);
  int2*   pk   = (int2*)((char*)d_ws + o_pk);

  hipMemsetAsync(hist, 0, hist_bytes, stream);
  hist_kernel<<<(BATCH * NPIX) / 256, 256, 0, stream>>>(in, out, hist);
  scan_kernel<<<BATCH, 1024, 0, stream>>>(hist, off, cur);
  scatter_kernel<<<(BATCH * NPIX) / 256, 256, 0, stream>>>(in, cur, emb, pk);
  cluster_kernel<<<BATCH, 1024, 0, stream>>>(in, out, emb, pk, off);
}

// Round 4
// 1494.019 us; speedup vs baseline: 4.0498x; 1.1577x over previous
//
#include <hip/hip_runtime.h>
#include <math.h>

#define BATCH 4
#define HH 512
#define WW 1024
#define NPIX (HH*WW)          // 524288 = 2^19
#define CCAP 196608           // compaction capacity per image (expected ~161.7k valid)
#define GX 64
#define GY 48
#define NCELL (GX*GY)         // 3072 cells, 0.0625 x 0.0625 over [-1,3]x[-1,2]

// ---------------- XLA:CPU f32 math replicas (unchanged from passing rounds) ----
__device__ __forceinline__ float xla_tanhf(float x) {
  if (fabsf(x) < 0.0004f) return x;
  float xc = fminf(fmaxf(x, -7.90531110763549805f), 7.90531110763549805f);
  float x2 = __fmul_rn(xc, xc);
  float p = -2.76076847742355e-16f;
  p = fmaf(x2, p, 2.00018790482477e-13f);
  p = fmaf(x2, p, -8.60467152213735e-11f);
  p = fmaf(x2, p, 5.12229709037114e-08f);
  p = fmaf(x2, p, 1.48572235717979e-05f);
  p = fmaf(x2, p, 6.37261928875436e-04f);
  p = fmaf(x2, p, 4.89352455891786e-03f);
  p = __fmul_rn(xc, p);
  float q = fmaf(x2, 1.19825839466702e-06f, 1.18534705686654e-04f);
  q = fmaf(x2, q, 2.26843463243900e-03f);
  q = fmaf(x2, q, 4.89352518554385e-03f);
  return __fdiv_rn(p, q);
}

__device__ __forceinline__ float xla_expf(float x) {
  float xc = fminf(fmaxf(x, -87.3365478515625f), 88.72283935546875f);
  float m = floorf(fmaf(xc, 1.44269504088896341f, 0.5f));
  float r = fmaf(m, -0.693359375f, xc);
  r = fmaf(m, 2.12194440e-4f, r);
  float r2 = __fmul_rn(r, r);
  float p = 1.9875691500e-4f;
  p = fmaf(p, r, 1.3981999507e-3f);
  p = fmaf(p, r, 8.3334519073e-3f);
  p = fmaf(p, r, 4.1665795894e-2f);
  p = fmaf(p, r, 1.6666665459e-1f);
  p = fmaf(p, r, 5.0000001201e-1f);
  float y = fmaf(r2, p, r);
  y = __fadd_rn(y, 1.0f);
  return ldexpf(y, (int)m);
}

__device__ __forceinline__ float xla_sigmoidf(float x) {
  return fmaf(0.5f, xla_tanhf(__fmul_rn(0.5f, x)), 0.5f);
}

// Proposal test — byte-identical decision logic to the passing kernels.
__device__ __forceinline__ bool prop_test(float2 e, float cx, float cy,
                                          float den0, float den1,
                                          float inv0, float inv1) {
  float d0 = __fsub_rn(e.x, cx), d1 = __fsub_rn(e.y, cy);
  float dd0 = __fmul_rn(d0, d0), dd1 = __fmul_rn(d1, d1);
  float zf = fmaf(dd0, inv0, __fmul_rn(dd1, inv1));
  if (zf < 0.6921472f) return true;
  if (zf <= 0.6941472f) {
    float t0 = __fdiv_rn(dd0, den0);
    float t1 = __fdiv_rn(dd1, den1);
    float z = __fadd_rn(t0, t1);
    return xla_expf(-z) > 0.5f;
  }
  return false;
}

__device__ __forceinline__ int cell_of_x(float ex) {
  int c = (int)((ex + 1.0f) * 16.0f);
  return min(max(c, 0), GX - 1);
}
__device__ __forceinline__ int cell_of_y(float ey) {
  int c = (int)((ey + 1.0f) * 16.0f);
  return min(max(c, 0), GY - 1);
}

// ---------------- kernels ----------------

__global__ __launch_bounds__(1024) void fill_kernel(int* out, int val, int n) {
  int i = blockIdx.x * 1024 + threadIdx.x;
  if (i < n) out[i] = val;
}

// pass A: zero output, histogram valid pixels into embedding-space cells
__global__ __launch_bounds__(256) void hist_kernel(const float* __restrict__ in,
                                                   int* __restrict__ out,
                                                   int* __restrict__ hist) {
  int gid = blockIdx.x * 256 + threadIdx.x;
  int b = gid >> 19;
  int p = gid & (NPIX - 1);
  const float* base = in + (size_t)b * 5 * NPIX;
  float seed = base[(size_t)4 * NPIX + p];
  out[gid] = 0;
  if (seed > 0.5f) {
    float ox = base[p];
    float oy = base[(size_t)NPIX + p];
    int col = p & (WW - 1);
    int row = p >> 10;
    float gx = __fmul_rn((float)col, 2.0f / 1023.0f);
    float gy = __fmul_rn((float)row, 1.0f / 511.0f);
    float ex = __fadd_rn(xla_tanhf(ox), gx);
    float ey = __fadd_rn(xla_tanhf(oy), gy);
    atomicAdd(&hist[b * NCELL + cell_of_y(ey) * GX + cell_of_x(ex)], 1);
  }
}

// pass B: exclusive scan of the 3072 cell counts per image (one block per image)
__global__ __launch_bounds__(1024) void scan_kernel(const int* __restrict__ hist,
                                                    int* __restrict__ off,
                                                    int* __restrict__ cursor) {
  __shared__ int s_c[NCELL];
  __shared__ int s_ps[1024];
  int b = blockIdx.x, t = threadIdx.x;
  const int* h = hist + b * NCELL;
  for (int i = t; i < NCELL; i += 1024) s_c[i] = h[i];
  __syncthreads();
  int a = s_c[3 * t], b2 = s_c[3 * t + 1], c2 = s_c[3 * t + 2];
  int th = a + b2 + c2;
  s_ps[t] = th;
  __syncthreads();
  for (int d = 1; d < 1024; d <<= 1) {
    int v = (t >= d) ? s_ps[t - d] : 0;
    __syncthreads();
    s_ps[t] += v;
    __syncthreads();
  }
  int excl = s_ps[t] - th;
  int* ob = off + b * (NCELL + 1);
  int* cb = cursor + b * NCELL;
  ob[3 * t] = excl;              cb[3 * t] = excl;
  ob[3 * t + 1] = excl + a;      cb[3 * t + 1] = excl + a;
  ob[3 * t + 2] = excl + a + b2; cb[3 * t + 2] = excl + a + b2;
  if (t == 1023) ob[NCELL] = s_ps[1023];
}

// pass C: scatter valid pixels into cell-sorted order (recomputes emb; deterministic)
__global__ __launch_bounds__(256) void scatter_kernel(const float* __restrict__ in,
                                                      int* __restrict__ cursor,
                                                      float2* __restrict__ emb,
                                                      int2* __restrict__ pk) {
  int gid = blockIdx.x * 256 + threadIdx.x;
  int b = gid >> 19;
  int p = gid & (NPIX - 1);
  const float* base = in + (size_t)b * 5 * NPIX;
  float seed = base[(size_t)4 * NPIX + p];
  if (seed > 0.5f) {
    float ox = base[p];
    float oy = base[(size_t)NPIX + p];
    int col = p & (WW - 1);
    int row = p >> 10;
    float gx = __fmul_rn((float)col, 2.0f / 1023.0f);
    float gy = __fmul_rn((float)row, 1.0f / 511.0f);
    float ex = __fadd_rn(xla_tanhf(ox), gx);
    float ey = __fadd_rn(xla_tanhf(oy), gy);
    float smv = xla_sigmoidf(seed);
    int cell = cell_of_y(ey) * GX + cell_of_x(ex);
    int slot = atomicAdd(&cursor[b * NCELL + cell], 1);
    if (slot < CCAP) {
      emb[(size_t)b * CCAP + slot] = make_float2(ex, ey);
      pk[(size_t)b * CCAP + slot]  = make_int2(__float_as_int(smv), p);
    }
  }
}

// One workgroup per image: greedy loop. 3 barriers/iteration:
//   pass1 (prop+count+remove+dirty) -> B1 -> [labels if accept] + dirty rescans
//   -> B2 -> argmax over segment keys (atomicMax) -> B3
__global__ __launch_bounds__(1024) void cluster_kernel(const float* __restrict__ in,
                                                       int* __restrict__ out,
                                                       const float2* __restrict__ emb_all,
                                                       const int2* __restrict__ pk_all,
                                                       const int* __restrict__ off_g) {
  __shared__ unsigned int s_uncl[CCAP / 32];            // 24 KB
  __shared__ int s_off[NCELL + 1];                      // 12 KB
  __shared__ unsigned long long s_segkey[CCAP / 64];    // 24 KB
  __shared__ int s_dirty[CCAP / 64];                    // 12 KB
  __shared__ unsigned long long s_bestkey[2];
  __shared__ int s_pc[2];
  __shared__ int s_uc[2];

  int b = blockIdx.x;
  int tid = threadIdx.x;
  int lane = tid & 63;
  int wid = tid >> 6;
  const int* offb = off_g + b * (NCELL + 1);
  int V = offb[NCELL];
  const float2* emb = emb_all + (size_t)b * CCAP;
  const int2*   pk  = pk_all  + (size_t)b * CCAP;
  int* outb = out + (size_t)b * NPIX;
  const float* base = in + (size_t)b * 5 * NPIX;

  if (V > CCAP) {   // capacity overflow marker
    for (int i = tid; i < NPIX; i += 1024) outb[i] = 1000000;
    return;
  }
  int NSEG = (V + 63) >> 6;

  for (int i = tid; i <= NCELL; i += 1024) s_off[i] = offb[i];
  for (int w = tid; w < CCAP / 32; w += 1024) {
    int basebit = w << 5;
    unsigned m;
    if (basebit + 32 <= V)      m = 0xffffffffu;
    else if (basebit >= V)      m = 0u;
    else                        m = (1u << (V - basebit)) - 1u;
    s_uncl[w] = m;
  }
  for (int s = tid; s < CCAP / 64; s += 1024) s_dirty[s] = 0;
  if (tid < 2) { s_bestkey[tid] = 0ULL; s_pc[tid] = 0; s_uc[tid] = 0; }
  __syncthreads();

  // build segment keys (all pixels unclustered initially)
  for (int s = wid; s < NSEG; s += 16) {
    int i = (s << 6) + lane;
    unsigned long long k = 0ULL;
    if (i < V) {
      int2 v = pk[i];
      k = ((unsigned long long)(unsigned)v.x << 32) | (unsigned)(~v.y);
    }
    for (int o = 32; o > 0; o >>= 1) {
      unsigned long long ok = __shfl_down(k, o);
      if (ok > k) k = ok;
    }
    if (lane == 0) s_segkey[s] = k;
  }
  __syncthreads();

  // initial argmax into slot 0
  {
    unsigned long long k = 0ULL;
    for (int s = tid; s < NSEG; s += 1024) {
      unsigned long long v = s_segkey[s];
      if (v > k) k = v;
    }
    for (int o = 32; o > 0; o >>= 1) {
      unsigned long long ok = __shfl_down(k, o);
      if (ok > k) k = ok;
    }
    if (lane == 0) atomicMax(&s_bestkey[0], k);
  }
  __syncthreads();

  int ucount = V, count = 1, guard = 0;
  int t = 0;
  while (ucount > 64 && guard++ <= CCAP) {
    int cur = t & 1, nxt = cur ^ 1;
    unsigned long long key = s_bestkey[cur];
    if (key == 0ULL) break;
    float sm = __uint_as_float((unsigned)(key >> 32));
    if (sm < 0.5f) break;              // ref's new_done (provably never fires)
    int px = (int)(~(unsigned)key);

    // ---- phase A: all threads redundantly compute center params (broadcast loads) ----
    float ox = base[px];
    float oy = base[(size_t)NPIX + px];
    float sx = base[(size_t)2 * NPIX + px];
    float sy = base[(size_t)3 * NPIX + px];
    int scol = px & (WW - 1);
    int srow = px >> 10;
    float cgx = __fmul_rn((float)scol, 2.0f / 1023.0f);
    float cgy = __fmul_rn((float)srow, 1.0f / 511.0f);
    float cx = __fadd_rn(xla_tanhf(ox), cgx);    // bit-identical to scatter's emb
    float cy = __fadd_rn(xla_tanhf(oy), cgy);
    float den0 = __fmul_rn(2.0f, __fmul_rn(sx, sx));
    float den1 = __fmul_rn(2.0f, __fmul_rn(sy, sy));
    float inv0 = 1.0f / den0;
    float inv1 = 1.0f / den1;
    float ry = sqrtf(__fmul_rn(den1, 0.6971472f)) * 1.00001f;
    int r0 = cell_of_y(cy - ry);
    int r1 = cell_of_y(cy + ry);

    // ---- pass 1: prop + pc/uc + removal + dirty marking (per-row tightened cols) ----
    int pc = 0, uc = 0;
    for (int r = r0; r <= r1; ++r) {
      float ylo = fmaf((float)r, 0.0625f, -1.0f);
      float dy = fmaxf(0.0f, fmaxf(ylo - cy, cy - (ylo + 0.0625f))) * 0.999999f;
      float rem = 0.6971472f - dy * dy * inv1;
      if (rem <= 0.0f) continue;
      float dxm = sqrtf(den0 * rem) * 1.00001f;
      int c0 = cell_of_x(cx - dxm), c1 = cell_of_x(cx + dxm);
      int rs = s_off[r * GX + c0], re = s_off[r * GX + c1 + 1];
      for (int i = rs + tid; i < re; i += 1024) {
        if (prop_test(emb[i], cx, cy, den0, den1, inv0, inv1)) {
          pc++;
          int w = i >> 5; unsigned bit = 1u << (i & 31);
          if (s_uncl[w] & bit) {
            atomicAnd(&s_uncl[w], ~bit);
            uc++;
            s_dirty[i >> 6] = 1;
          }
        }
      }
    }
    for (int o = 32; o > 0; o >>= 1) {
      pc += __shfl_down(pc, o);
      uc += __shfl_down(uc, o);
    }
    if (lane == 0 && (pc | uc)) {
      if (pc) atomicAdd(&s_pc[cur], pc);
      if (uc) atomicAdd(&s_uc[cur], uc);
    }
    __syncthreads();   // B1

    int pcT = s_pc[cur];
    int ucR = s_uc[cur];            // total removed this iter (includes seed)
    bool accept = (pcT > 64) && (2 * (ucR - 1) > pcT);  // ref uc excludes seed
    int label = count & 255;
    if (accept) count++;
    ucount -= ucR;
    if (tid == 0) { s_pc[nxt] = 0; s_uc[nxt] = 0; s_bestkey[nxt] = 0ULL; }

    // ---- labels (rare) ----
    if (accept) {
      for (int r = r0; r <= r1; ++r) {
        float ylo = fmaf((float)r, 0.0625f, -1.0f);
        float dy = fmaxf(0.0f, fmaxf(ylo - cy, cy - (ylo + 0.0625f))) * 0.999999f;
        float rem = 0.6971472f - dy * dy * inv1;
        if (rem <= 0.0f) continue;
        float dxm = sqrtf(den0 * rem) * 1.00001f;
        int c0 = cell_of_x(cx - dxm), c1 = cell_of_x(cx + dxm);
        int rs = s_off[r * GX + c0], re = s_off[r * GX + c1 + 1];
        for (int i = rs + tid; i < re; i += 1024) {
          if (prop_test(emb[i], cx, cy, den0, den1, inv0, inv1)) {
            outb[pk[i].y] = label;
          }
        }
      }
    }

    // ---- dirty segment rescans (wave-owned: s % 16 == wid) ----
    for (int r = r0; r <= r1; ++r) {
      float ylo = fmaf((float)r, 0.0625f, -1.0f);
      float dy = fmaxf(0.0f, fmaxf(ylo - cy, cy - (ylo + 0.0625f))) * 0.999999f;
      float rem = 0.6971472f - dy * dy * inv1;
      if (rem <= 0.0f) continue;
      float dxm = sqrtf(den0 * rem) * 1.00001f;
      int c0 = cell_of_x(cx - dxm), c1 = cell_of_x(cx + dxm);
      int rs = s_off[r * GX + c0], re = s_off[r * GX + c1 + 1];
      if (re <= rs) continue;
      int slo = rs >> 6, shi = (re - 1) >> 6;
      for (int s = slo + ((wid - slo) & 15); s <= shi; s += 16) {
        if (s_dirty[s]) {
          if (lane == 0) s_dirty[s] = 0;
          int i = (s << 6) + lane;
          unsigned long long k = 0ULL;
          if (i < V && ((s_uncl[i >> 5] >> (i & 31)) & 1u)) {
            int2 v = pk[i];
            k = ((unsigned long long)(unsigned)v.x << 32) | (unsigned)(~v.y);
          }
          for (int o = 32; o > 0; o >>= 1) {
            unsigned long long ok = __shfl_down(k, o);
            if (ok > k) k = ok;
          }
          if (lane == 0) s_segkey[s] = k;
        }
      }
    }
    __syncthreads();   // B2

    // ---- argmax over segment keys into next slot ----
    {
      unsigned long long k = 0ULL;
      for (int s = tid; s < NSEG; s += 1024) {
        unsigned long long v = s_segkey[s];
        if (v > k) k = v;
      }
      for (int o = 32; o > 0; o >>= 1) {
        unsigned long long ok = __shfl_down(k, o);
        if (ok > k) k = ok;
      }
      if (lane == 0) atomicMax(&s_bestkey[nxt], k);
    }
    __syncthreads();   // B3
    t++;
  }
}

// ---------------- launch ----------------

extern "C" void kernel_launch(void* const* d_in, const int* in_sizes, int n_in,
                              void* d_out, int out_size, void* d_ws, size_t ws_size,
                              hipStream_t stream) {
  const float* in = (const float*)d_in[0];
  int* out = (int*)d_out;

  size_t hist_bytes = (size_t)BATCH * NCELL * sizeof(int);
  size_t off_bytes  = (size_t)BATCH * (NCELL + 1) * sizeof(int);
  size_t cur_bytes  = (size_t)BATCH * NCELL * sizeof(int);
  size_t emb_bytes  = (size_t)BATCH * CCAP * sizeof(float2);
  size_t pk_bytes   = (size_t)BATCH * CCAP * sizeof(int2);

  size_t o_hist = 256;
  size_t o_off  = (o_hist + hist_bytes + 255) & ~(size_t)255;
  size_t o_cur  = (o_off + off_bytes + 255) & ~(size_t)255;
  size_t o_emb  = (o_cur + cur_bytes + 255) & ~(size_t)255;
  size_t o_pk   = (o_emb + emb_bytes + 255) & ~(size_t)255;
  size_t need   = o_pk + pk_bytes;

  if (ws_size < need) {
    fill_kernel<<<(out_size + 1023) / 1024, 1024, 0, stream>>>(out, 2000000, out_size);
    return;
  }

  int*    hist = (int*)((char*)d_ws + o_hist);
  int*    off  = (int*)((char*)d_ws + o_off);
  int*    cur  = (int*)((char*)d_ws + o_cur);
  float2* emb  = (float2*)((char*)d_ws + o_emb);
  int2*   pk   = (int2*)((char*)d_ws + o_pk);

  hipMemsetAsync(hist, 0, hist_bytes, stream);
  hist_kernel<<<(BATCH * NPIX) / 256, 256, 0, stream>>>(in, out, hist);
  scan_kernel<<<BATCH, 1024, 0, stream>>>(hist, off, cur);
  scatter_kernel<<<(BATCH * NPIX) / 256, 256, 0, stream>>>(in, cur, emb, pk);
  cluster_kernel<<<BATCH, 1024, 0, stream>>>(in, out, emb, pk, off);
}